// Round 1
// baseline (292.655 us; speedup 1.0000x reference)
//
#include <hip/hip_runtime.h>

#define GEPS 1e-10f

// ---------------------------------------------------------------------------
// Fused kernel: one block (1024 threads) per batch row b.
//
// Phase 1 (pool): thread t owns channel row (b, t): 196 floats = 49 float4,
//   contiguous 784 B. 49 independent float4 loads per lane (unroll 7) give
//   deep MLP with no cross-lane reduction at all; result -> LDS sp[1024].
//   Per CU (16 waves): ~114 KB loads in flight vs ~9 KB needed for 6.3 TB/s.
//
// Phase 2 (head): a = t&31 (action), seg = t>>5 (32-channel segment).
//   partial[seg][a] = dot(sp[seg*32:+32], w[a, seg*32:+32])   (w is L2-hot,
//   pooled reads are LDS half-wave broadcasts -> conflict-free).
//   logits -> +gumbel (argmax-invariant reduction of the softmax/temperature
//   chain) -> first-max argmax (matches jnp.argmax tie-break) ->
//   out[b] = amax; out[256 + b*1024 : +1024] = gates[amax, :].
// ---------------------------------------------------------------------------
__global__ __launch_bounds__(1024) void fused_kernel(
    const float* __restrict__ x,
    const float* __restrict__ gumbel_u,
    const float* __restrict__ w,
    const float* __restrict__ gates,
    float* __restrict__ out)
{
    const int b = blockIdx.x;
    const int t = threadIdx.x;

    __shared__ float sp[1024];        // pooled[b, :]
    __shared__ float partial[32][32]; // [seg][a] — write addr == t, conflict-free
    __shared__ float score[32];
    __shared__ int   s_amax;

    // ---------------- Phase 1: pooled[b, t] = mean(relu(x[b, t, :, :])) ----
    {
        const float4* row = (const float4*)(x + ((size_t)b * 1024 + t) * 196);
        float s = 0.0f;
        #pragma unroll 7
        for (int j = 0; j < 49; ++j) {
            float4 v = row[j];
            s += fmaxf(v.x, 0.0f) + fmaxf(v.y, 0.0f) +
                 fmaxf(v.z, 0.0f) + fmaxf(v.w, 0.0f);
        }
        sp[t] = s * (1.0f / 196.0f);
    }
    __syncthreads();

    // ---------------- Phase 2a: segmented dot products ---------------------
    const int a   = t & 31;   // action
    const int seg = t >> 5;   // 32-channel segment, 0..31
    {
        const float4* wr = (const float4*)(w + (size_t)a * 1024 + seg * 32);
        const float4* pp = (const float4*)(sp + seg * 32);  // LDS broadcast
        float acc = 0.0f;
        #pragma unroll
        for (int i = 0; i < 8; ++i) {
            float4 wv = wr[i];
            float4 pv = pp[i];
            acc += wv.x * pv.x + wv.y * pv.y + wv.z * pv.z + wv.w * pv.w;
        }
        partial[seg][a] = acc;   // linear addr == t
    }
    __syncthreads();

    // ---------------- Phase 2b: logits + gumbel ----------------------------
    if (t < 32) {
        float logit = 0.0f;
        #pragma unroll
        for (int s2 = 0; s2 < 32; ++s2) logit += partial[s2][t];  // lanes consecutive
        float u = gumbel_u[b * 32 + t];
        float g = -logf(-logf(u + GEPS) + GEPS);
        score[t] = logit + g;
    }
    __syncthreads();

    // ---------------- Phase 2c: first-max argmax ---------------------------
    if (t == 0) {
        int amax = 0;
        float best = score[0];
        #pragma unroll
        for (int i = 1; i < 32; ++i) {
            if (score[i] > best) { best = score[i]; amax = i; }  // strict > => first max
        }
        s_amax = amax;
        out[b] = (float)amax;   // sampled_actions as float32
    }
    __syncthreads();

    // ---------------- Phase 2d: gates row copy -----------------------------
    const int amax = s_amax;
    if (t < 256) {
        float4 gv = ((const float4*)(gates + (size_t)amax * 1024))[t];
        ((float4*)(out + 256 + (size_t)b * 1024))[t] = gv;
    }
}

extern "C" void kernel_launch(void* const* d_in, const int* in_sizes, int n_in,
                              void* d_out, int out_size, void* d_ws, size_t ws_size,
                              hipStream_t stream) {
    const float* x        = (const float*)d_in[0];  // [256,1024,14,14]
    const float* gumbel_u = (const float*)d_in[1];  // [256,32]
    const float* fc1_w    = (const float*)d_in[2];  // [32,1024]
    const float* gates    = (const float*)d_in[3];  // [32,1024]
    float* out = (float*)d_out;                     // [256 + 256*1024]

    fused_kernel<<<256, 1024, 0, stream>>>(x, gumbel_u, fc1_w, gates, out);
}

// Round 4
// 265.324 us; speedup vs baseline: 1.1030x; 1.1030x over previous
//
#include <hip/hip_runtime.h>

#define GEPS 1e-10f

typedef float floatx4 __attribute__((ext_vector_type(4)));

__device__ __forceinline__ float relusum4(floatx4 v) {
    return fmaxf(v.x, 0.0f) + fmaxf(v.y, 0.0f) + fmaxf(v.z, 0.0f) + fmaxf(v.w, 0.0f);
}

// ---------------------------------------------------------------------------
// Fused kernel: one block (1024 threads = 16 waves) per batch row b.
//
// Phase 1 (pool, coalesced + wave-private LDS transpose):
//   Wave w owns channels [w*64, w*64+64) of x[b] (64 ch x 196 fl = 12544 fl),
//   processed as two 32-channel halves (1568 float4s each):
//     - load: lane l reads float4 k*64+l  -> 1 KB contiguous per wave-instr
//       (fully coalesced, vs stride-784B per-lane streaming in round 1),
//       relu-sums 4 elements, writes scalar to wave-private
//       stage[w][k*64+l] (consecutive addrs -> 2-way bank alias, free).
//     - reduce: 2 lanes per channel read 49 contiguous stage floats
//       (addr (17c+25h+j) mod 32 = exact 2-way alias, free), one
//       __shfl_xor combine, even lane writes sp[channel].
//   Stage is wave-private -> no __syncthreads inside phase 1.
//   Loads are nontemporal: x is 205 MB/iter streaming, don't evict L2-hot w.
//
// Phase 2 (head): a = t&31 (action), seg = t>>5 (32-channel segment).
//   partial[seg][a] = dot(sp[seg*32:+32], w[a, seg*32:+32])  (w L2-resident,
//   sp reads are half-wave broadcasts). Then logits + gumbel (argmax-
//   invariant reduction of log_softmax/temperature/softmax chain),
//   first-max argmax (matches jnp.argmax), gates row copy.
// ---------------------------------------------------------------------------
__global__ __launch_bounds__(1024) void fused_kernel(
    const float* __restrict__ x,
    const float* __restrict__ gumbel_u,
    const float* __restrict__ wfc,
    const float* __restrict__ gates,
    float* __restrict__ out)
{
    const int b = blockIdx.x;
    const int t = threadIdx.x;
    const int w = t >> 6;   // wave 0..15
    const int l = t & 63;   // lane

    __shared__ float stage[16][1568];   // 100 KB, wave-private slabs
    __shared__ float sp[1024];          // pooled[b, :]
    __shared__ float partial[32][32];   // [seg][a] — write addr == t
    __shared__ float score[32];
    __shared__ int   s_amax;

    // ---------------- Phase 1: pooled ---------------------------------
    {
        const floatx4* x4 = (const floatx4*)x;
        float* st = stage[w];
        #pragma unroll
        for (int h = 0; h < 2; ++h) {
            // 32 channels = 1568 float4s = 24*64 + 32
            const floatx4* src = x4 + ((size_t)b * 1024 + w * 64 + h * 32) * 49;
            #pragma unroll 8
            for (int k = 0; k < 24; ++k) {
                floatx4 v = __builtin_nontemporal_load(&src[k * 64 + l]);
                st[k * 64 + l] = relusum4(v);
            }
            if (l < 32) {
                floatx4 v = __builtin_nontemporal_load(&src[1536 + l]);
                st[1536 + l] = relusum4(v);
            }
            // wave-internal ds_write -> ds_read dependency; compiler waits
            const int c2  = l >> 1;       // local channel 0..31
            const int odd = l & 1;
            const float* sbase = st + c2 * 49 + odd * 25;
            float ssum = 0.0f;
            #pragma unroll
            for (int j = 0; j < 24; ++j) ssum += sbase[j];
            if (!odd) ssum += sbase[24];  // even lane covers 25 elems (0..24)
            ssum += __shfl_xor(ssum, 1, 64);
            if (!odd) sp[w * 64 + h * 32 + c2] = ssum * (1.0f / 196.0f);
        }
    }
    __syncthreads();

    // ---------------- Phase 2a: segmented dot products ------------------
    const int a   = t & 31;   // action
    const int seg = t >> 5;   // 32-channel segment, 0..31
    {
        const float4* wr = (const float4*)(wfc + (size_t)a * 1024 + seg * 32);
        const float4* pp = (const float4*)(sp + seg * 32);  // half-wave broadcast
        float acc = 0.0f;
        #pragma unroll
        for (int i = 0; i < 8; ++i) {
            float4 wv = wr[i];
            float4 pv = pp[i];
            acc += wv.x * pv.x + wv.y * pv.y + wv.z * pv.z + wv.w * pv.w;
        }
        partial[seg][a] = acc;   // linear addr == t, conflict-free
    }
    __syncthreads();

    // ---------------- Phase 2b: logits + gumbel -------------------------
    if (t < 32) {
        float logit = 0.0f;
        #pragma unroll
        for (int s2 = 0; s2 < 32; ++s2) logit += partial[s2][t];
        float u = gumbel_u[b * 32 + t];
        float g = -logf(-logf(u + GEPS) + GEPS);
        score[t] = logit + g;
    }
    __syncthreads();

    // ---------------- Phase 2c: first-max argmax ------------------------
    if (t == 0) {
        int amax = 0;
        float best = score[0];
        #pragma unroll
        for (int i = 1; i < 32; ++i) {
            if (score[i] > best) { best = score[i]; amax = i; }  // strict >
        }
        s_amax = amax;
        out[b] = (float)amax;   // sampled_actions as float32
    }
    __syncthreads();

    // ---------------- Phase 2d: gates row copy --------------------------
    const int amax = s_amax;
    if (t < 256) {
        float4 gv = ((const float4*)(gates + (size_t)amax * 1024))[t];
        ((float4*)(out + 256 + (size_t)b * 1024))[t] = gv;
    }
}

extern "C" void kernel_launch(void* const* d_in, const int* in_sizes, int n_in,
                              void* d_out, int out_size, void* d_ws, size_t ws_size,
                              hipStream_t stream) {
    const float* x        = (const float*)d_in[0];  // [256,1024,14,14]
    const float* gumbel_u = (const float*)d_in[1];  // [256,32]
    const float* fc1_w    = (const float*)d_in[2];  // [32,1024]
    const float* gates    = (const float*)d_in[3];  // [32,1024]
    float* out = (float*)d_out;                     // [256 + 256*1024]

    fused_kernel<<<256, 1024, 0, stream>>>(x, gumbel_u, fc1_w, gates, out);
}